// Round 1
// 4430.468 us; speedup vs baseline: 2.0498x; 2.0498x over previous
//
#include <hip/hip_runtime.h>
#include <hip/hip_bf16.h>

#define N_NODES 262144
#define N_EDGES 1048576
#define NC      30
#define ED      13
#define H       256
#define GH      512
#define OUT_C   256
#define NLAYERS 4
#define NGRAPHS 8192

typedef __hip_bfloat16 bf16;
typedef __attribute__((ext_vector_type(8))) short short8;   // 8 bf16 = 4 VGPR
typedef __attribute__((ext_vector_type(4))) float f32x4;

// packed weights: bf16, N-major (Bt[n][k], k contiguous) + fp32 biases
__device__ unsigned short g_W1t[H * H];
__device__ unsigned short g_Wl1t[2][H * H];
__device__ unsigned short g_Wl2t[2][H * H];
__device__ float g_b1[H];
__device__ float g_bl1[GH];
__device__ float g_bl2[OUT_C];

__device__ __forceinline__ float hw2f(unsigned short h) {
    return __uint_as_float(((unsigned int)h) << 16);
}
__device__ __forceinline__ float ldf(const void* p, size_t i, bool isbf) {
    return isbf ? hw2f(((const unsigned short*)p)[i]) : ((const float*)p)[i];
}
__device__ __forceinline__ int ldi(const void* p, size_t j, bool is64) {
    return ((const int*)p)[is64 ? 2 * j : j];   // little-endian lo word
}
__device__ __forceinline__ unsigned short bfbits(float f) {
    bf16 b = __float2bfloat16(f);
    return *(unsigned short*)&b;
}
__device__ __forceinline__ float lo16(unsigned int u) { return __uint_as_float(u << 16); }
__device__ __forceinline__ float hi16(unsigned int u) { return __uint_as_float(u & 0xFFFF0000u); }
__device__ __forceinline__ unsigned int pk2(float a, float b) {
    return (unsigned int)bfbits(a) | ((unsigned int)bfbits(b) << 16);
}
// float width sniff: even halfwords. bf16 data -> plausible exponents.
__device__ __forceinline__ bool sniff_bf16(const void* xv) {
    const unsigned short* q = (const unsigned short*)xv;
    int c = 0;
    for (int i = 0; i < 32; ++i) {
        unsigned short h = q[2 * i];
        int e = (h >> 7) & 0xFF;
        c += (h == 0 || (e >= 97 && e <= 141)) ? 1 : 0;
    }
    return c >= 20;
}
// int width sniff: odd 32-bit words all zero <=> int64 (values < 2^31).
__device__ __forceinline__ bool sniff_i64(const void* pv, size_t baseWord) {
    const unsigned int* q = (const unsigned int*)pv;
    int z = 0;
    for (int i = 0; i < 32; ++i) z += (q[baseWord + 2 * i + 1] == 0) ? 1 : 0;
    return z >= 20;
}
// packed bf16x2 add via 32-bit CAS (avg in-degree 4: low contention)
__device__ __forceinline__ void cas_add_bf16x2(unsigned int* addr, float v0, float v1) {
    unsigned int old = __hip_atomic_load(addr, __ATOMIC_RELAXED,
                                         __HIP_MEMORY_SCOPE_AGENT);
    unsigned int assumed;
    do {
        assumed = old;
        float a0 = __uint_as_float((assumed & 0xFFFFu) << 16);
        float a1 = __uint_as_float(assumed & 0xFFFF0000u);
        unsigned int nv = (unsigned int)bfbits(a0 + v0) |
                          ((unsigned int)bfbits(a1 + v1) << 16);
        old = atomicCAS(addr, assumed, nv);
    } while (old != assumed);
}
// async global->LDS, 16B per lane; dst is wave-uniform base + lane*16
__device__ __forceinline__ void gload_lds16(const void* g, void* l) {
    __builtin_amdgcn_global_load_lds(
        (const __attribute__((address_space(1))) unsigned int*)g,
        (__attribute__((address_space(3))) unsigned int*)l, 16, 0, 0);
}

// ---------------------------------------------------------------- fills
__global__ __launch_bounds__(256) void fill_f4(float4* p, int n4, float val) {
    int i = blockIdx.x * 256 + threadIdx.x;
    int stride = gridDim.x * 256;
    float4 z = make_float4(val, val, val, val);
    for (; i < n4; i += stride) p[i] = z;
}

// ---------------------------------------------------- weight / bias packers
// out[n][k] = in[k0+k][n0+n]  (transpose + bf16-normalize), 256x256 chunk
__global__ __launch_bounds__(256) void pack_wt(const void* __restrict__ in,
        int ldin, int k0, int n0, int which) {
    const bool isbf = sniff_bf16(in);
    unsigned short* outp = which == 0 ? g_W1t
                         : which == 1 ? g_Wl1t[0]
                         : which == 2 ? g_Wl1t[1]
                         : which == 3 ? g_Wl2t[0] : g_Wl2t[1];
    const int n = blockIdx.x, k = threadIdx.x;
    outp[(n << 8) + k] = bfbits(ldf(in, (size_t)(k0 + k) * ldin + n0 + n, isbf));
}
__global__ __launch_bounds__(256) void pack_bias(const void* b1, const void* bl1,
                                                 const void* bl2) {
    const int t = threadIdx.x;
    const bool s1 = sniff_bf16(b1), s2 = sniff_bf16(bl1), s3 = sniff_bf16(bl2);
    g_b1[t]        = ldf(b1,  t,       s1);
    g_bl1[t]       = ldf(bl1, t,       s2);
    g_bl1[t + 256] = ldf(bl1, t + 256, s2);
    g_bl2[t]       = ldf(bl2, t,       s3);
}

// ------------------------------------------------- hid = x @ W_nh + b_nh
__global__ __launch_bounds__(256) void node_proj(
        const void* __restrict__ x, const void* __restrict__ W,
        const void* __restrict__ b, bf16* __restrict__ hid) {
    const bool isbf = sniff_bf16(x);
    __shared__ float xs[16 * NC];
    const int m0 = blockIdx.x * 16;
    for (int i = threadIdx.x; i < 16 * NC; i += 256)
        xs[i] = ldf(x, (size_t)m0 * NC + i, isbf);
    __syncthreads();
    const int col = threadIdx.x;
    float w[NC];
#pragma unroll
    for (int k = 0; k < NC; ++k) w[k] = ldf(W, (size_t)k * H + col, isbf);
    const float bias = ldf(b, col, isbf);
#pragma unroll 4
    for (int r = 0; r < 16; ++r) {
        float acc = bias;
#pragma unroll
        for (int k = 0; k < NC; ++k) acc += xs[r * NC + k] * w[k];
        hid[(size_t)(m0 + r) * H + col] = __float2bfloat16(acc);
    }
}

// ---- per-edge, all edges one pass (hid = layer-l values everywhere):
// e = eattr@We[l]+be[l] ; msg = relu(hid[src]+e) ; agg[dst] += msg
// AGGB=0: fp32 agg, plain atomicAdd.  AGGB=1: bf16 agg, packed CAS add.
template <int AGGB>
__global__ __launch_bounds__(256) void edge_full(
        const void* __restrict__ eattr, const void* __restrict__ eidx,
        const void* __restrict__ We, size_t weOff,
        const void* __restrict__ be, size_t beOff,
        const bf16* __restrict__ hid,
        float* __restrict__ aggf, unsigned int* __restrict__ aggb) {
    const bool isbf = sniff_bf16(eattr);
    const bool is64 = sniff_i64(eidx, 0);
    __shared__ float Ws[ED * H];
    __shared__ float bs[H];
    for (int i = threadIdx.x; i < ED * H; i += 256)
        Ws[i] = ldf(We, weOff + i, isbf);
    for (int i = threadIdx.x; i < H; i += 256)
        bs[i] = ldf(be, beOff + i, isbf);
    __syncthreads();
    const int wave = threadIdx.x >> 6;
    const int lane = threadIdx.x & 63;
    const int e0 = blockIdx.x * 64;
    for (int it = 0; it < 16; ++it) {
        const int e = e0 + it * 4 + wave;
        int src = ldi(eidx, e, is64);
        int dst = ldi(eidx, (size_t)N_EDGES + e, is64);
        if ((unsigned)src >= (unsigned)N_NODES) src = 0;   // safety clamp
        if ((unsigned)dst >= (unsigned)N_NODES) dst = 0;
        float af[ED];
        for (int k = 0; k < ED; ++k)
            af[k] = ldf(eattr, (size_t)e * ED + k, isbf);
        const unsigned short* hrow = (const unsigned short*)hid + (size_t)src * H;
        if (AGGB == 0) {
            float* arow = aggf + (size_t)dst * H;
#pragma unroll
            for (int j = 0; j < 4; ++j) {
                const int col = lane + 64 * j;
                float v = bs[col];
#pragma unroll
                for (int k = 0; k < ED; ++k) v += af[k] * Ws[k * H + col];
                v += hw2f(hrow[col]);
                atomicAdd(arow + col, fmaxf(v, 0.f));
            }
        } else {
            unsigned int* arow = aggb + (size_t)dst * (H / 2);
#pragma unroll
            for (int j = 0; j < 2; ++j) {
                const int c0 = 2 * lane + 128 * j;
                float v0 = bs[c0], v1 = bs[c0 + 1];
#pragma unroll
                for (int k = 0; k < ED; ++k) {
                    v0 += af[k] * Ws[k * H + c0];
                    v1 += af[k] * Ws[k * H + c0 + 1];
                }
                unsigned int h2 = *(const unsigned int*)(hrow + c0);
                v0 += __uint_as_float((h2 & 0xFFFFu) << 16);
                v1 += __uint_as_float(h2 & 0xFFFF0000u);
                cas_add_bf16x2(arow + lane + 64 * j, fmaxf(v0, 0.f), fmaxf(v1, 0.f));
            }
        }
    }
}

// ------------------------------------------------------------ MFMA GEMM
// C[M,256] = act( (widen(A) [+A2f|+widen(A2b)]) @ Bt^T + bias )
// Bt: device-global bf16 [256 n][256 k] (k-contiguous), selected by bsel.
// BM=64 BN=256 BK=64; 4 waves (2 row-groups x 2 col-groups); 16x16x32 MFMA.
// A/B fragments use one consistent (group,slot)->k map, which cancels in the
// contraction; C/D layout is the verified col=lane&15, row=4*(lane>>4)+reg.
// LDS XOR-swizzle ((row&7)<<4 on 16B slots) kills the stride-128B conflict;
// B staged via global_load_lds (linear dest, inverse-swizzled source).
// MODE 0: Cb = bf16(act(..)); in-place over A safe (block owns its 64 rows).
// MODE 1: fp32 atomicAdd pooled by batch[] into Cf[g*OUT_C+col] (sorted batch).
template <int MODE>
__global__ __launch_bounds__(256) void gemm_mfma(
        const unsigned short* __restrict__ A, const float* __restrict__ A2f,
        const unsigned short* __restrict__ A2b, int bsel,
        unsigned short* __restrict__ Cb, float* __restrict__ Cf,
        const void* __restrict__ batch, size_t batOff, int doRelu, int useBias) {
    __shared__ unsigned short As[64 * 64];    // 8 KB, swizzled
    __shared__ unsigned short Bs[256 * 64];   // 32 KB, n-major [n][k], swizzled
    const int tid  = threadIdx.x;
    const int lane = tid & 63;
    const int wave = tid >> 6;
    const int m0   = blockIdx.x * 64;

    const unsigned short* Bt = bsel == 0 ? g_W1t
                             : bsel == 1 ? g_Wl1t[0]
                             : bsel == 2 ? g_Wl1t[1]
                             : bsel == 3 ? g_Wl2t[0] : g_Wl2t[1];
    const float* bias = bsel == 0 ? g_b1
                      : bsel == 1 ? g_bl1
                      : bsel == 2 ? g_bl1 + 256 : g_bl2;

    // A staging: thread -> (row ar, 16 k-elems at ac)
    const int ar   = tid >> 2;
    const int ac   = (tid & 3) << 4;
    const int awb  = (ar << 7) + (ac << 1);
    const int aswz = (ar & 7) << 4;
    const size_t arow = (size_t)(m0 + ar) * H + ac;
    // B staging: 8x 1KB chunks per wave; lane source pre-inverse-swizzled
    const int nrow = lane >> 3;
    const int kbu  = ((lane & 7) ^ nrow) << 4;

    f32x4 acc0[8], acc1[8];
    const f32x4 zz = {0.f, 0.f, 0.f, 0.f};
#pragma unroll
    for (int i = 0; i < 8; ++i) { acc0[i] = zz; acc1[i] = zz; }

    const int fr   = lane & 15;
    const int fg   = lane >> 4;
    const int rowb = (wave >> 1) << 5;   // 0 / 32
    const int colb = (wave & 1) << 7;    // 0 / 128

    for (int kt = 0; kt < 4; ++kt) {
        // ---- B tile (32 KB): async direct-to-LDS
#pragma unroll
        for (int j = 0; j < 8; ++j) {
            const int q = (wave << 3) + j;
            gload_lds16((const char*)Bt + (((size_t)(q << 3) + nrow) << 9)
                            + (kt << 7) + kbu,
                        (char*)Bs + (q << 10));
        }
        // ---- A tile (8 KB): regs (+agg add, bf16 round) -> swizzled LDS
        {
            const size_t aoff = arow + (kt << 6);
            uint4 h0 = *(const uint4*)(A + aoff);
            uint4 h1 = *(const uint4*)(A + aoff + 8);
            uint4 w0 = h0, w1 = h1;
            if (A2f) {
                const float4* gp = (const float4*)(A2f + aoff);
                float4 g0 = gp[0], g1 = gp[1], g2 = gp[2], g3 = gp[3];
                w0.x = pk2(lo16(h0.x) + g0.x, hi16(h0.x) + g0.y);
                w0.y = pk2(lo16(h0.y) + g0.z, hi16(h0.y) + g0.w);
                w0.z = pk2(lo16(h0.z) + g1.x, hi16(h0.z) + g1.y);
                w0.w = pk2(lo16(h0.w) + g1.z, hi16(h0.w) + g1.w);
                w1.x = pk2(lo16(h1.x) + g2.x, hi16(h1.x) + g2.y);
                w1.y = pk2(lo16(h1.y) + g2.z, hi16(h1.y) + g2.w);
                w1.z = pk2(lo16(h1.z) + g3.x, hi16(h1.z) + g3.y);
                w1.w = pk2(lo16(h1.w) + g3.z, hi16(h1.w) + g3.w);
            } else if (A2b) {
                uint4 b0  = *(const uint4*)(A2b + aoff);
                uint4 b1v = *(const uint4*)(A2b + aoff + 8);
                w0.x = pk2(lo16(h0.x) + lo16(b0.x),  hi16(h0.x) + hi16(b0.x));
                w0.y = pk2(lo16(h0.y) + lo16(b0.y),  hi16(h0.y) + hi16(b0.y));
                w0.z = pk2(lo16(h0.z) + lo16(b0.z),  hi16(h0.z) + hi16(b0.z));
                w0.w = pk2(lo16(h0.w) + lo16(b0.w),  hi16(h0.w) + hi16(b0.w));
                w1.x = pk2(lo16(h1.x) + lo16(b1v.x), hi16(h1.x) + hi16(b1v.x));
                w1.y = pk2(lo16(h1.y) + lo16(b1v.y), hi16(h1.y) + hi16(b1v.y));
                w1.z = pk2(lo16(h1.z) + lo16(b1v.z), hi16(h1.z) + hi16(b1v.z));
                w1.w = pk2(lo16(h1.w) + lo16(b1v.w), hi16(h1.w) + hi16(b1v.w));
            }
            *(uint4*)((char*)As + (awb ^ aswz)) = w0;
            *(uint4*)((char*)As + ((awb + 16) ^ aswz)) = w1;
        }
        __syncthreads();   // drains vmcnt (global_load_lds) + lgkmcnt
        // ---- compute: 2 k-slices x (2 row-tiles x 8 col-tiles)
#pragma unroll
        for (int s = 0; s < 2; ++s) {
            const int kofs = (s << 6) + (fg << 4);
            const int r0 = rowb + fr;
            short8 aF0 = *(const short8*)((const char*)As +
                          ((r0 << 7) + (kofs ^ ((r0 & 7) << 4))));
            short8 aF1 = *(const short8*)((const char*)As +
                          (((r0 + 16) << 7) + (kofs ^ ((r0 & 7) << 4))));
#pragma unroll
            for (int ct = 0; ct < 8; ++ct) {
                const int cc = colb + (ct << 4) + fr;
                short8 bF = *(const short8*)((const char*)Bs +
                             ((cc << 7) + (kofs ^ ((cc & 7) << 4))));
                acc0[ct] = __builtin_amdgcn_mfma_f32_16x16x32_bf16(aF0, bF, acc0[ct], 0, 0, 0);
                acc1[ct] = __builtin_amdgcn_mfma_f32_16x16x32_bf16(aF1, bF, acc1[ct], 0, 0, 0);
            }
        }
        __syncthreads();
    }

    const int crow = m0 + rowb + (fg << 2);
    if (MODE == 0) {
#pragma unroll
        for (int ct = 0; ct < 8; ++ct) {
            const int cc = colb + (ct << 4) + fr;
            const float bc = bias[cc];
#pragma unroll
            for (int r = 0; r < 4; ++r) {
                float v0 = acc0[ct][r] + bc;
                float v1 = acc1[ct][r] + bc;
                if (doRelu) { v0 = fmaxf(v0, 0.f); v1 = fmaxf(v1, 0.f); }
                Cb[(size_t)(crow + r) * H + cc]      = bfbits(v0);
                Cb[(size_t)(crow + 16 + r) * H + cc] = bfbits(v1);
            }
        }
    } else {
        const bool is64 = sniff_i64(batch, N_NODES / 2);
        int ga[5], gb[5];
#pragma unroll
        for (int r = 0; r < 4; ++r) {
            int g0 = ldi(batch, batOff + crow + r, is64);
            int g1 = ldi(batch, batOff + crow + 16 + r, is64);
            ga[r] = ((unsigned)g0 < (unsigned)NGRAPHS) ? g0 : 0;   // safety clamp
            gb[r] = ((unsigned)g1 < (unsigned)NGRAPHS) ? g1 : 0;
        }
#pragma unroll
        for (int ct = 0; ct < 8; ++ct) {
            const int cc = colb + (ct << 4) + fr;
            const float bc = useBias ? bias[cc] : 0.f;
            float run0 = 0.f, run1 = 0.f;
#pragma unroll
            for (int r = 0; r < 4; ++r) {
                run0 += acc0[ct][r] + bc;
                if (r == 3 || ga[r + 1] != ga[r]) {
                    atomicAdd(&Cf[(size_t)ga[r] * OUT_C + cc], run0); run0 = 0.f;
                }
                run1 += acc1[ct][r] + bc;
                if (r == 3 || gb[r + 1] != gb[r]) {
                    atomicAdd(&Cf[(size_t)gb[r] * OUT_C + cc], run1); run1 = 0.f;
                }
            }
        }
    }
}

// ---------------------------------------------------------------- launcher
extern "C" void kernel_launch(void* const* d_in, const int* in_sizes, int n_in,
                              void* d_out, int out_size, void* d_ws, size_t ws_size,
                              hipStream_t stream) {
    // size-based input mapping (proven == dict order in R6/R7)
    const void *x = nullptr, *eattr = nullptr, *eidx = nullptr, *batch = nullptr;
    const void *W_nh = nullptr, *W1 = nullptr, *We = nullptr, *be = nullptr;
    const void *Wl1 = nullptr, *Wl2 = nullptr, *bl1 = nullptr;
    const void *z256[3] = {nullptr, nullptr, nullptr};
    int nz = 0;
    for (int i = 0; i < n_in; ++i) {
        switch (in_sizes[i]) {
            case N_NODES * NC:     x     = d_in[i]; break;
            case N_EDGES * ED:     eattr = d_in[i]; break;
            case 2 * N_EDGES:      eidx  = d_in[i]; break;
            case N_NODES:          batch = d_in[i]; break;
            case NC * H:           W_nh  = d_in[i]; break;
            case H * H:            W1    = d_in[i]; break;
            case NLAYERS * ED * H: We    = d_in[i]; break;
            case NLAYERS * H:      be    = d_in[i]; break;
            case H * GH:           if (!Wl1) Wl1 = d_in[i]; else Wl2 = d_in[i]; break;
            case GH:               bl1   = d_in[i]; break;
            case H:                if (nz < 3) z256[nz++] = d_in[i]; break;
            default: break;
        }
    }
    const void* b_nh = z256[0];
    const void* b1   = (nz > 1) ? z256[1] : z256[0];
    const void* bl2  = (nz > 2) ? z256[2] : z256[0];
    float* out = (float*)d_out;   // reference output dtype is FLOAT32

    if (!x || !eattr || !eidx || !batch || !W_nh || !W1 || !We || !be ||
        !Wl1 || !Wl2 || !bl1 || !b_nh) {
        fill_f4<<<1024, 256, 0, stream>>>((float4*)out, NGRAPHS * OUT_C / 4, 2.0e6f);
        return;  // sentinel: size-mapping failed
    }

    const size_t NH = (size_t)N_NODES * H;
    const size_t needA = NH * 4 + NH * 2;   // fp32 agg + bf16 hid = 384 MiB
    const size_t needB = NH * 2 + NH * 2;   // bf16 agg + bf16 hid = 256 MiB

    float* aggf = nullptr;
    unsigned int* aggb = nullptr;
    bf16* hid;
    if (ws_size >= needA) {
        aggf = (float*)d_ws;
        hid  = (bf16*)((char*)d_ws + NH * 4);
    } else if (ws_size >= needB) {
        aggb = (unsigned int*)d_ws;
        hid  = (bf16*)((char*)d_ws + NH * 2);
    } else {
        fill_f4<<<1024, 256, 0, stream>>>((float4*)out, NGRAPHS * OUT_C / 4, 1.0e6f);
        return;  // sentinel: ws too small
    }

    // pack weights (transposed, bf16) + biases (fp32) into device globals
    pack_wt<<<256, 256, 0, stream>>>(W1,  H,     0,   0, 0);
    pack_wt<<<256, 256, 0, stream>>>(Wl1, GH,    0,   0, 1);
    pack_wt<<<256, 256, 0, stream>>>(Wl1, GH,    0, 256, 2);
    pack_wt<<<256, 256, 0, stream>>>(Wl2, OUT_C, 0,   0, 3);
    pack_wt<<<256, 256, 0, stream>>>(Wl2, OUT_C, 256, 0, 4);
    pack_bias<<<1, 256, 0, stream>>>(b1, bl1, bl2);

    node_proj<<<N_NODES / 16, 256, 0, stream>>>(x, W_nh, b_nh, hid);

    for (int l = 0; l < NLAYERS; ++l) {
        if (aggf) {
            fill_f4<<<8192, 256, 0, stream>>>((float4*)aggf, (int)(NH / 4), 0.f);
            edge_full<0><<<N_EDGES / 64, 256, 0, stream>>>(
                eattr, eidx, We, (size_t)l * ED * H, be, (size_t)l * H,
                hid, aggf, nullptr);
        } else {
            fill_f4<<<8192, 256, 0, stream>>>((float4*)aggb, (int)(NH * 2 / 16), 0.f);
            edge_full<1><<<N_EDGES / 64, 256, 0, stream>>>(
                eattr, eidx, We, (size_t)l * ED * H, be, (size_t)l * H,
                hid, nullptr, aggb);
        }
        // hid = relu((hid + agg) @ W1 + b1), in-place (block owns its rows)
        gemm_mfma<0><<<N_NODES / 64, 256, 0, stream>>>(
            (const unsigned short*)hid, aggf, (const unsigned short*)aggb,
            0, (unsigned short*)hid, nullptr, nullptr, 0, 1, 1);
    }

    // readout: t1 = relu(hid@Wl1+bl1); out[g] += t1@Wl2 + bl2 pooled by batch.
    // GH split into 2 k/n chunks of 256; t0 = full [N,256] bf16 (128 MiB),
    // aliases the dead agg region at d_ws.
    unsigned short* t0 = (unsigned short*)d_ws;
    fill_f4<<<2048, 256, 0, stream>>>((float4*)out, NGRAPHS * OUT_C / 4, 0.f);
    for (int c = 0; c < 2; ++c) {
        gemm_mfma<0><<<N_NODES / 64, 256, 0, stream>>>(
            (const unsigned short*)hid, nullptr, nullptr, 1 + c,
            t0, nullptr, nullptr, 0, 1, 1);
        gemm_mfma<1><<<N_NODES / 64, 256, 0, stream>>>(
            t0, nullptr, nullptr, 3 + c,
            nullptr, out, batch, 0, 0, c == 0);
    }
}

// Round 2
// 4383.305 us; speedup vs baseline: 2.0718x; 1.0108x over previous
//
#include <hip/hip_runtime.h>
#include <hip/hip_bf16.h>

#define N_NODES 262144
#define N_EDGES 1048576
#define NC      30
#define ED      13
#define H       256
#define GH      512
#define OUT_C   256
#define NLAYERS 4
#define NGRAPHS 8192

typedef __hip_bfloat16 bf16;
typedef __attribute__((ext_vector_type(8))) short short8;   // 8 bf16 = 4 VGPR
typedef __attribute__((ext_vector_type(4))) float f32x4;

// packed weights: bf16, N-major (Bt[n][k], k contiguous) + fp32 biases
__device__ unsigned short g_W1t[H * H];
__device__ unsigned short g_Wl1t[2][H * H];
__device__ unsigned short g_Wl2t[2][H * H];
__device__ float g_b1[H];
__device__ float g_bl1[GH];
__device__ float g_bl2[OUT_C];

__device__ __forceinline__ float hw2f(unsigned short h) {
    return __uint_as_float(((unsigned int)h) << 16);
}
__device__ __forceinline__ float ldf(const void* p, size_t i, bool isbf) {
    return isbf ? hw2f(((const unsigned short*)p)[i]) : ((const float*)p)[i];
}
__device__ __forceinline__ int ldi(const void* p, size_t j, bool is64) {
    return ((const int*)p)[is64 ? 2 * j : j];   // little-endian lo word
}
__device__ __forceinline__ unsigned short bfbits(float f) {
    bf16 b = __float2bfloat16(f);
    return *(unsigned short*)&b;
}
__device__ __forceinline__ float lo16(unsigned int u) { return __uint_as_float(u << 16); }
__device__ __forceinline__ float hi16(unsigned int u) { return __uint_as_float(u & 0xFFFF0000u); }
__device__ __forceinline__ unsigned int pk2(float a, float b) {
    return (unsigned int)bfbits(a) | ((unsigned int)bfbits(b) << 16);
}
// float width sniff: even halfwords. bf16 data -> plausible exponents.
__device__ __forceinline__ bool sniff_bf16(const void* xv) {
    const unsigned short* q = (const unsigned short*)xv;
    int c = 0;
    for (int i = 0; i < 32; ++i) {
        unsigned short h = q[2 * i];
        int e = (h >> 7) & 0xFF;
        c += (h == 0 || (e >= 97 && e <= 141)) ? 1 : 0;
    }
    return c >= 20;
}
// int width sniff: odd 32-bit words all zero <=> int64 (values < 2^31).
__device__ __forceinline__ bool sniff_i64(const void* pv, size_t baseWord) {
    const unsigned int* q = (const unsigned int*)pv;
    int z = 0;
    for (int i = 0; i < 32; ++i) z += (q[baseWord + 2 * i + 1] == 0) ? 1 : 0;
    return z >= 20;
}
// packed bf16x2 add via 32-bit CAS (fallback path only)
__device__ __forceinline__ void cas_add_bf16x2(unsigned int* addr, float v0, float v1) {
    unsigned int old = __hip_atomic_load(addr, __ATOMIC_RELAXED,
                                         __HIP_MEMORY_SCOPE_AGENT);
    unsigned int assumed;
    do {
        assumed = old;
        float a0 = __uint_as_float((assumed & 0xFFFFu) << 16);
        float a1 = __uint_as_float(assumed & 0xFFFF0000u);
        unsigned int nv = (unsigned int)bfbits(a0 + v0) |
                          ((unsigned int)bfbits(a1 + v1) << 16);
        old = atomicCAS(addr, assumed, nv);
    } while (old != assumed);
}
// async global->LDS, 16B per lane; dst is wave-uniform base + lane*16
__device__ __forceinline__ void gload_lds16(const void* g, void* l) {
    __builtin_amdgcn_global_load_lds(
        (const __attribute__((address_space(1))) unsigned int*)g,
        (__attribute__((address_space(3))) unsigned int*)l, 16, 0, 0);
}

// ---------------------------------------------------------------- fills
__global__ __launch_bounds__(256) void fill_f4(float4* p, int n4, float val) {
    int i = blockIdx.x * 256 + threadIdx.x;
    int stride = gridDim.x * 256;
    float4 z = make_float4(val, val, val, val);
    for (; i < n4; i += stride) p[i] = z;
}

// ---------------------------------------------------- weight / bias packers
// out[n][k] = in[k0+k][n0+n]  (transpose + bf16-normalize), 256x256 chunk
__global__ __launch_bounds__(256) void pack_wt(const void* __restrict__ in,
        int ldin, int k0, int n0, int which) {
    const bool isbf = sniff_bf16(in);
    unsigned short* outp = which == 0 ? g_W1t
                         : which == 1 ? g_Wl1t[0]
                         : which == 2 ? g_Wl1t[1]
                         : which == 3 ? g_Wl2t[0] : g_Wl2t[1];
    const int n = blockIdx.x, k = threadIdx.x;
    outp[(n << 8) + k] = bfbits(ldf(in, (size_t)(k0 + k) * ldin + n0 + n, isbf));
}
__global__ __launch_bounds__(256) void pack_bias(const void* b1, const void* bl1,
                                                 const void* bl2) {
    const int t = threadIdx.x;
    const bool s1 = sniff_bf16(b1), s2 = sniff_bf16(bl1), s3 = sniff_bf16(bl2);
    g_b1[t]        = ldf(b1,  t,       s1);
    g_bl1[t]       = ldf(bl1, t,       s2);
    g_bl1[t + 256] = ldf(bl1, t + 256, s2);
    g_bl2[t]       = ldf(bl2, t,       s3);
}

// ------------------------------------------------------------- CSR build
// edge_index is launch-invariant across layers: sort edges by dst ONCE.
__global__ __launch_bounds__(256) void hist_dst(const void* __restrict__ eidx,
                                                unsigned int* __restrict__ cnt) {
    const bool is64 = sniff_i64(eidx, 0);
    const int e = blockIdx.x * 256 + threadIdx.x;
    int dst = ldi(eidx, (size_t)N_EDGES + e, is64);
    if ((unsigned)dst >= (unsigned)N_NODES) dst = 0;
    atomicAdd(&cnt[dst], 1u);
}
__global__ __launch_bounds__(256) void scan1(const unsigned int* __restrict__ cnt,
                                             unsigned int* __restrict__ bsum) {
    __shared__ unsigned int sh[256];
    const int tid = threadIdx.x;
    sh[tid] = cnt[blockIdx.x * 256 + tid];
    __syncthreads();
    for (int s = 128; s > 0; s >>= 1) {
        if (tid < s) sh[tid] += sh[tid + s];
        __syncthreads();
    }
    if (tid == 0) bsum[blockIdx.x] = sh[0];
}
__global__ __launch_bounds__(256) void scan2(unsigned int* bsum) {
    __shared__ unsigned int sh[1024];
    const int tid = threadIdx.x;
    for (int j = tid; j < 1024; j += 256) sh[j] = bsum[j];
    __syncthreads();
    if (tid == 0) {
        unsigned int run = 0;
        for (int j = 0; j < 1024; ++j) { unsigned int t = sh[j]; sh[j] = run; run += t; }
    }
    __syncthreads();
    for (int j = tid; j < 1024; j += 256) bsum[j] = sh[j];
}
// rowptr[i] = exclusive-scan(cnt)[i]; cursor[i] = rowptr[i]. cnt MAY alias cursor
// (each thread reads its own slot into LDS before any write). No __restrict__.
__global__ __launch_bounds__(256) void scan3(const unsigned int* cnt,
                                             const unsigned int* bsum,
                                             unsigned int* rowptr,
                                             unsigned int* cursor) {
    __shared__ unsigned int sh[256];
    const int tid = threadIdx.x;
    const int i = blockIdx.x * 256 + tid;
    const unsigned int v = cnt[i];
    sh[tid] = v;
    __syncthreads();
    for (int ofs = 1; ofs < 256; ofs <<= 1) {
        unsigned int t = (tid >= ofs) ? sh[tid - ofs] : 0u;
        __syncthreads();
        sh[tid] += t;
        __syncthreads();
    }
    const unsigned int excl = sh[tid] - v + bsum[blockIdx.x];
    rowptr[i] = excl;
    cursor[i] = excl;
    if (i == N_NODES - 1) rowptr[N_NODES] = excl + v;
}
// scatter src-ids and edge_attr rows into dst-sorted order
__global__ __launch_bounds__(256) void scatter_e(
        const void* __restrict__ eidx, const void* __restrict__ eattr,
        unsigned int* __restrict__ cursor, unsigned int* __restrict__ ssrc,
        float* __restrict__ seat) {
    const bool is64 = sniff_i64(eidx, 0);
    const bool isbf = sniff_bf16(eattr);
    const int e = blockIdx.x * 256 + threadIdx.x;
    int src = ldi(eidx, e, is64);
    int dst = ldi(eidx, (size_t)N_EDGES + e, is64);
    if ((unsigned)src >= (unsigned)N_NODES) src = 0;
    if ((unsigned)dst >= (unsigned)N_NODES) dst = 0;
    unsigned int pos = atomicAdd(&cursor[dst], 1u);
    if (pos >= (unsigned)N_EDGES) return;   // safety (cannot happen if hist consistent)
    ssrc[pos] = (unsigned int)src;
#pragma unroll
    for (int k = 0; k < ED; ++k)
        seat[(size_t)pos * ED + k] = ldf(eattr, (size_t)e * ED + k, isbf);
}

// ------------------------------------------------- hid = x @ W_nh + b_nh
__global__ __launch_bounds__(256) void node_proj(
        const void* __restrict__ x, const void* __restrict__ W,
        const void* __restrict__ b, bf16* __restrict__ hid) {
    const bool isbf = sniff_bf16(x);
    __shared__ float xs[16 * NC];
    const int m0 = blockIdx.x * 16;
    for (int i = threadIdx.x; i < 16 * NC; i += 256)
        xs[i] = ldf(x, (size_t)m0 * NC + i, isbf);
    __syncthreads();
    const int col = threadIdx.x;
    float w[NC];
#pragma unroll
    for (int k = 0; k < NC; ++k) w[k] = ldf(W, (size_t)k * H + col, isbf);
    const float bias = ldf(b, col, isbf);
#pragma unroll 4
    for (int r = 0; r < 16; ++r) {
        float acc = bias;
#pragma unroll
        for (int k = 0; k < NC; ++k) acc += xs[r * NC + k] * w[k];
        hid[(size_t)(m0 + r) * H + col] = __float2bfloat16(acc);
    }
}

// --------------------------------------------- CSR aggregation (no atomics)
// hsum[n] = hid[n] + sum_{e in in(n)} relu(hid[src(e)] + eattr_s[e]@We + be)
// One wave per node (4 nodes per wave sequentially, 16 per block).
// LDS layout Ws[k][256] + col = lane+64j is the proven conflict-free pattern
// (edge_full showed SQ_LDS_BANK_CONFLICT == 0 with it).
__global__ __launch_bounds__(256) void gine_agg(
        const unsigned int* __restrict__ rowptr,
        const unsigned int* __restrict__ ssrc,
        const float* __restrict__ seat,
        const void* __restrict__ We, size_t weOff,
        const void* __restrict__ be, size_t beOff,
        const unsigned short* __restrict__ hid,
        unsigned short* __restrict__ hsum) {
    const bool isbf = sniff_bf16(We);
    __shared__ float Ws[ED * H];
    __shared__ float bs[H];
    for (int i = threadIdx.x; i < ED * H; i += 256)
        Ws[i] = ldf(We, weOff + i, isbf);
    for (int i = threadIdx.x; i < H; i += 256)
        bs[i] = ldf(be, beOff + i, isbf);
    __syncthreads();
    const int wave = threadIdx.x >> 6;
    const int lane = threadIdx.x & 63;
    const int n0 = blockIdx.x * 16 + wave * 4;
    for (int ni = 0; ni < 4; ++ni) {
        const int node = n0 + ni;
        const unsigned int r0 = rowptr[node], r1 = rowptr[node + 1];
        const unsigned short* hn = hid + (size_t)node * H;
        float acc[4];
#pragma unroll
        for (int j = 0; j < 4; ++j) acc[j] = hw2f(hn[lane + 64 * j]);
        for (unsigned int e = r0; e < r1; ++e) {
            const unsigned int s = ssrc[e];
            const unsigned short* hs = hid + (size_t)s * H;
            const float* af = seat + (size_t)e * ED;
            float a[ED];
#pragma unroll
            for (int k = 0; k < ED; ++k) a[k] = af[k];
#pragma unroll
            for (int j = 0; j < 4; ++j) {
                const int col = lane + 64 * j;
                float v = bs[col];
#pragma unroll
                for (int k = 0; k < ED; ++k) v += a[k] * Ws[k * H + col];
                v += hw2f(hs[col]);
                acc[j] += fmaxf(v, 0.f);
            }
        }
        unsigned short* ho = hsum + (size_t)node * H;
#pragma unroll
        for (int j = 0; j < 4; ++j) ho[lane + 64 * j] = bfbits(acc[j]);
    }
}

// ---- fallback per-edge kernel (small-ws path only): bf16 agg, packed CAS
__global__ __launch_bounds__(256) void edge_full_cas(
        const void* __restrict__ eattr, const void* __restrict__ eidx,
        const void* __restrict__ We, size_t weOff,
        const void* __restrict__ be, size_t beOff,
        const bf16* __restrict__ hid, unsigned int* __restrict__ aggb) {
    const bool isbf = sniff_bf16(eattr);
    const bool is64 = sniff_i64(eidx, 0);
    __shared__ float Ws[ED * H];
    __shared__ float bs[H];
    for (int i = threadIdx.x; i < ED * H; i += 256)
        Ws[i] = ldf(We, weOff + i, isbf);
    for (int i = threadIdx.x; i < H; i += 256)
        bs[i] = ldf(be, beOff + i, isbf);
    __syncthreads();
    const int wave = threadIdx.x >> 6;
    const int lane = threadIdx.x & 63;
    const int e0 = blockIdx.x * 64;
    for (int it = 0; it < 16; ++it) {
        const int e = e0 + it * 4 + wave;
        int src = ldi(eidx, e, is64);
        int dst = ldi(eidx, (size_t)N_EDGES + e, is64);
        if ((unsigned)src >= (unsigned)N_NODES) src = 0;
        if ((unsigned)dst >= (unsigned)N_NODES) dst = 0;
        float af[ED];
        for (int k = 0; k < ED; ++k)
            af[k] = ldf(eattr, (size_t)e * ED + k, isbf);
        const unsigned short* hrow = (const unsigned short*)hid + (size_t)src * H;
        unsigned int* arow = aggb + (size_t)dst * (H / 2);
#pragma unroll
        for (int j = 0; j < 2; ++j) {
            const int c0 = 2 * lane + 128 * j;
            float v0 = bs[c0], v1 = bs[c0 + 1];
#pragma unroll
            for (int k = 0; k < ED; ++k) {
                v0 += af[k] * Ws[k * H + c0];
                v1 += af[k] * Ws[k * H + c0 + 1];
            }
            unsigned int h2 = *(const unsigned int*)(hrow + c0);
            v0 += __uint_as_float((h2 & 0xFFFFu) << 16);
            v1 += __uint_as_float(h2 & 0xFFFF0000u);
            cas_add_bf16x2(arow + lane + 64 * j, fmaxf(v0, 0.f), fmaxf(v1, 0.f));
        }
    }
}

// ------------------------------------------------------------ MFMA GEMM
// C[M,256] = act( (widen(A) [+widen(A2b)]) @ Bt^T + bias )
// Bt: device-global bf16 [256 n][256 k] (k-contiguous), selected by bsel.
// BM=64 BN=256 BK=64; 4 waves; 16x16x32 MFMA; verified C/D layout
// col=lane&15, row=4*(lane>>4)+reg. LDS XOR-swizzle on 16B slots.
// MODE 0: Cb = bf16(act(..)).  MODE 1: fp32 atomicAdd pooled by batch[].
template <int MODE>
__global__ __launch_bounds__(256) void gemm_mfma(
        const unsigned short* __restrict__ A,
        const unsigned short* __restrict__ A2b, int bsel,
        unsigned short* __restrict__ Cb, float* __restrict__ Cf,
        const void* __restrict__ batch, size_t batOff, int doRelu, int useBias) {
    __shared__ unsigned short As[64 * 64];    // 8 KB, swizzled
    __shared__ unsigned short Bs[256 * 64];   // 32 KB, n-major [n][k], swizzled
    const int tid  = threadIdx.x;
    const int lane = tid & 63;
    const int wave = tid >> 6;
    const int m0   = blockIdx.x * 64;

    const unsigned short* Bt = bsel == 0 ? g_W1t
                             : bsel == 1 ? g_Wl1t[0]
                             : bsel == 2 ? g_Wl1t[1]
                             : bsel == 3 ? g_Wl2t[0] : g_Wl2t[1];
    const float* bias = bsel == 0 ? g_b1
                      : bsel == 1 ? g_bl1
                      : bsel == 2 ? g_bl1 + 256 : g_bl2;

    const int ar   = tid >> 2;
    const int ac   = (tid & 3) << 4;
    const int awb  = (ar << 7) + (ac << 1);
    const int aswz = (ar & 7) << 4;
    const size_t arow = (size_t)(m0 + ar) * H + ac;
    const int nrow = lane >> 3;
    const int kbu  = ((lane & 7) ^ nrow) << 4;

    f32x4 acc0[8], acc1[8];
    const f32x4 zz = {0.f, 0.f, 0.f, 0.f};
#pragma unroll
    for (int i = 0; i < 8; ++i) { acc0[i] = zz; acc1[i] = zz; }

    const int fr   = lane & 15;
    const int fg   = lane >> 4;
    const int rowb = (wave >> 1) << 5;   // 0 / 32
    const int colb = (wave & 1) << 7;    // 0 / 128

    for (int kt = 0; kt < 4; ++kt) {
#pragma unroll
        for (int j = 0; j < 8; ++j) {
            const int q = (wave << 3) + j;
            gload_lds16((const char*)Bt + (((size_t)(q << 3) + nrow) << 9)
                            + (kt << 7) + kbu,
                        (char*)Bs + (q << 10));
        }
        {
            const size_t aoff = arow + (kt << 6);
            uint4 h0 = *(const uint4*)(A + aoff);
            uint4 h1 = *(const uint4*)(A + aoff + 8);
            uint4 w0 = h0, w1 = h1;
            if (A2b) {
                uint4 b0  = *(const uint4*)(A2b + aoff);
                uint4 b1v = *(const uint4*)(A2b + aoff + 8);
                w0.x = pk2(lo16(h0.x) + lo16(b0.x),  hi16(h0.x) + hi16(b0.x));
                w0.y = pk2(lo16(h0.y) + lo16(b0.y),  hi16(h0.y) + hi16(b0.y));
                w0.z = pk2(lo16(h0.z) + lo16(b0.z),  hi16(h0.z) + hi16(b0.z));
                w0.w = pk2(lo16(h0.w) + lo16(b0.w),  hi16(h0.w) + hi16(b0.w));
                w1.x = pk2(lo16(h1.x) + lo16(b1v.x), hi16(h1.x) + hi16(b1v.x));
                w1.y = pk2(lo16(h1.y) + lo16(b1v.y), hi16(h1.y) + hi16(b1v.y));
                w1.z = pk2(lo16(h1.z) + lo16(b1v.z), hi16(h1.z) + hi16(b1v.z));
                w1.w = pk2(lo16(h1.w) + lo16(b1v.w), hi16(h1.w) + hi16(b1v.w));
            }
            *(uint4*)((char*)As + (awb ^ aswz)) = w0;
            *(uint4*)((char*)As + ((awb + 16) ^ aswz)) = w1;
        }
        __syncthreads();   // drains vmcnt (global_load_lds) + lgkmcnt
#pragma unroll
        for (int s = 0; s < 2; ++s) {
            const int kofs = (s << 6) + (fg << 4);
            const int r0 = rowb + fr;
            short8 aF0 = *(const short8*)((const char*)As +
                          ((r0 << 7) + (kofs ^ ((r0 & 7) << 4))));
            short8 aF1 = *(const short8*)((const char*)As +
                          (((r0 + 16) << 7) + (kofs ^ ((r0 & 7) << 4))));
#pragma unroll
            for (int ct = 0; ct < 8; ++ct) {
                const int cc = colb + (ct << 4) + fr;
                short8 bF = *(const short8*)((const char*)Bs +
                             ((cc << 7) + (kofs ^ ((cc & 7) << 4))));
                acc0[ct] = __builtin_amdgcn_mfma_f32_16x16x32_bf16(aF0, bF, acc0[ct], 0, 0, 0);
                acc1[ct] = __builtin_amdgcn_mfma_f32_16x16x32_bf16(aF1, bF, acc1[ct], 0, 0, 0);
            }
        }
        __syncthreads();
    }

    const int crow = m0 + rowb + (fg << 2);
    if (MODE == 0) {
#pragma unroll
        for (int ct = 0; ct < 8; ++ct) {
            const int cc = colb + (ct << 4) + fr;
            const float bc = bias[cc];
#pragma unroll
            for (int r = 0; r < 4; ++r) {
                float v0 = acc0[ct][r] + bc;
                float v1 = acc1[ct][r] + bc;
                if (doRelu) { v0 = fmaxf(v0, 0.f); v1 = fmaxf(v1, 0.f); }
                Cb[(size_t)(crow + r) * H + cc]      = bfbits(v0);
                Cb[(size_t)(crow + 16 + r) * H + cc] = bfbits(v1);
            }
        }
    } else {
        const bool is64 = sniff_i64(batch, N_NODES / 2);
        int ga[5], gb[5];
#pragma unroll
        for (int r = 0; r < 4; ++r) {
            int g0 = ldi(batch, batOff + crow + r, is64);
            int g1 = ldi(batch, batOff + crow + 16 + r, is64);
            ga[r] = ((unsigned)g0 < (unsigned)NGRAPHS) ? g0 : 0;
            gb[r] = ((unsigned)g1 < (unsigned)NGRAPHS) ? g1 : 0;
        }
#pragma unroll
        for (int ct = 0; ct < 8; ++ct) {
            const int cc = colb + (ct << 4) + fr;
            const float bc = useBias ? bias[cc] : 0.f;
            float run0 = 0.f, run1 = 0.f;
#pragma unroll
            for (int r = 0; r < 4; ++r) {
                run0 += acc0[ct][r] + bc;
                if (r == 3 || ga[r + 1] != ga[r]) {
                    atomicAdd(&Cf[(size_t)ga[r] * OUT_C + cc], run0); run0 = 0.f;
                }
                run1 += acc1[ct][r] + bc;
                if (r == 3 || gb[r + 1] != gb[r]) {
                    atomicAdd(&Cf[(size_t)gb[r] * OUT_C + cc], run1); run1 = 0.f;
                }
            }
        }
    }
}

// ---------------------------------------------------------------- launcher
extern "C" void kernel_launch(void* const* d_in, const int* in_sizes, int n_in,
                              void* d_out, int out_size, void* d_ws, size_t ws_size,
                              hipStream_t stream) {
    const void *x = nullptr, *eattr = nullptr, *eidx = nullptr, *batch = nullptr;
    const void *W_nh = nullptr, *W1 = nullptr, *We = nullptr, *be = nullptr;
    const void *Wl1 = nullptr, *Wl2 = nullptr, *bl1 = nullptr;
    const void *z256[3] = {nullptr, nullptr, nullptr};
    int nz = 0;
    for (int i = 0; i < n_in; ++i) {
        switch (in_sizes[i]) {
            case N_NODES * NC:     x     = d_in[i]; break;
            case N_EDGES * ED:     eattr = d_in[i]; break;
            case 2 * N_EDGES:      eidx  = d_in[i]; break;
            case N_NODES:          batch = d_in[i]; break;
            case NC * H:           W_nh  = d_in[i]; break;
            case H * H:            W1    = d_in[i]; break;
            case NLAYERS * ED * H: We    = d_in[i]; break;
            case NLAYERS * H:      be    = d_in[i]; break;
            case H * GH:           if (!Wl1) Wl1 = d_in[i]; else Wl2 = d_in[i]; break;
            case GH:               bl1   = d_in[i]; break;
            case H:                if (nz < 3) z256[nz++] = d_in[i]; break;
            default: break;
        }
    }
    const void* b_nh = z256[0];
    const void* b1   = (nz > 1) ? z256[1] : z256[0];
    const void* bl2  = (nz > 2) ? z256[2] : z256[0];
    float* out = (float*)d_out;   // reference output dtype is FLOAT32

    if (!x || !eattr || !eidx || !batch || !W_nh || !W1 || !We || !be ||
        !Wl1 || !Wl2 || !bl1 || !b_nh) {
        fill_f4<<<1024, 256, 0, stream>>>((float4*)out, NGRAPHS * OUT_C / 4, 2.0e6f);
        return;  // sentinel: size-mapping failed
    }

    const size_t NH = (size_t)N_NODES * H;
    // CSR-path workspace layout (bytes):
    const size_t oHsum = NH * 2;                               // after hid
    const size_t oSeat = NH * 4;
    const size_t oSsrc = oSeat + (size_t)N_EDGES * ED * 4;
    const size_t oRowp = oSsrc + (size_t)N_EDGES * 4;
    const size_t oCurs = oRowp + (size_t)(N_NODES + 4) * 4;    // keeps 16B align
    const size_t oBsum = oCurs + (size_t)N_NODES * 4;
    const size_t needCSR = oBsum + 1024 * 4;                   // ~314 MiB
    const size_t needB   = NH * 2 + NH * 2;                    // 256 MiB fallback

    // pack weights (transposed, bf16) + biases (fp32) into device globals
    pack_wt<<<256, 256, 0, stream>>>(W1,  H,     0,   0, 0);
    pack_wt<<<256, 256, 0, stream>>>(Wl1, GH,    0,   0, 1);
    pack_wt<<<256, 256, 0, stream>>>(Wl1, GH,    0, 256, 2);
    pack_wt<<<256, 256, 0, stream>>>(Wl2, OUT_C, 0,   0, 3);
    pack_wt<<<256, 256, 0, stream>>>(Wl2, OUT_C, 256, 0, 4);
    pack_bias<<<1, 256, 0, stream>>>(b1, bl1, bl2);

    if (ws_size >= needCSR) {
        char* w = (char*)d_ws;
        bf16* hid            = (bf16*)w;
        unsigned short* hsum = (unsigned short*)(w + oHsum);
        float* seat          = (float*)(w + oSeat);
        unsigned int* ssrc   = (unsigned int*)(w + oSsrc);
        unsigned int* rowptr = (unsigned int*)(w + oRowp);
        unsigned int* cursor = (unsigned int*)(w + oCurs);
        unsigned int* bsum   = (unsigned int*)(w + oBsum);

        // ---- build dst-sorted CSR once (edge_index is layer-invariant)
        fill_f4<<<1024, 256, 0, stream>>>((float4*)cursor, N_NODES * 4 / 16, 0.f);
        hist_dst<<<N_EDGES / 256, 256, 0, stream>>>(eidx, cursor);
        scan1<<<N_NODES / 256, 256, 0, stream>>>(cursor, bsum);
        scan2<<<1, 256, 0, stream>>>(bsum);
        scan3<<<N_NODES / 256, 256, 0, stream>>>(cursor, bsum, rowptr, cursor);
        scatter_e<<<N_EDGES / 256, 256, 0, stream>>>(eidx, eattr, cursor, ssrc, seat);

        node_proj<<<N_NODES / 16, 256, 0, stream>>>(x, W_nh, b_nh, hid);

        for (int l = 0; l < NLAYERS; ++l) {
            // hsum = hid + agg  (no atomics, no zero-fill, bf16 out)
            gine_agg<<<N_NODES / 16, 256, 0, stream>>>(
                rowptr, ssrc, seat, We, (size_t)l * ED * H, be, (size_t)l * H,
                (const unsigned short*)hid, hsum);
            // hid = relu(hsum @ W1 + b1)
            gemm_mfma<0><<<N_NODES / 64, 256, 0, stream>>>(
                hsum, nullptr, 0, (unsigned short*)hid,
                nullptr, nullptr, 0, 1, 1);
        }

        // readout; t0 aliases hsum (dead after last layer GEMM)
        unsigned short* t0 = hsum;
        fill_f4<<<2048, 256, 0, stream>>>((float4*)out, NGRAPHS * OUT_C / 4, 0.f);
        for (int c = 0; c < 2; ++c) {
            gemm_mfma<0><<<N_NODES / 64, 256, 0, stream>>>(
                (const unsigned short*)hid, nullptr, 1 + c,
                t0, nullptr, nullptr, 0, 1, 1);
            gemm_mfma<1><<<N_NODES / 64, 256, 0, stream>>>(
                t0, nullptr, 3 + c,
                nullptr, out, batch, 0, 0, c == 0);
        }
    } else if (ws_size >= needB) {
        // fallback: bf16 CAS aggregation (small workspace)
        unsigned int* aggb = (unsigned int*)d_ws;
        bf16* hid = (bf16*)((char*)d_ws + NH * 2);

        node_proj<<<N_NODES / 16, 256, 0, stream>>>(x, W_nh, b_nh, hid);
        for (int l = 0; l < NLAYERS; ++l) {
            fill_f4<<<8192, 256, 0, stream>>>((float4*)aggb, (int)(NH * 2 / 16), 0.f);
            edge_full_cas<<<N_EDGES / 64, 256, 0, stream>>>(
                eattr, eidx, We, (size_t)l * ED * H, be, (size_t)l * H,
                hid, aggb);
            gemm_mfma<0><<<N_NODES / 64, 256, 0, stream>>>(
                (const unsigned short*)hid, (const unsigned short*)aggb,
                0, (unsigned short*)hid, nullptr, nullptr, 0, 1, 1);
        }
        unsigned short* t0 = (unsigned short*)d_ws;
        fill_f4<<<2048, 256, 0, stream>>>((float4*)out, NGRAPHS * OUT_C / 4, 0.f);
        for (int c = 0; c < 2; ++c) {
            gemm_mfma<0><<<N_NODES / 64, 256, 0, stream>>>(
                (const unsigned short*)hid, nullptr, 1 + c,
                t0, nullptr, nullptr, 0, 1, 1);
            gemm_mfma<1><<<N_NODES / 64, 256, 0, stream>>>(
                t0, nullptr, 3 + c,
                nullptr, out, batch, 0, 0, c == 0);
        }
    } else {
        fill_f4<<<1024, 256, 0, stream>>>((float4*)out, NGRAPHS * OUT_C / 4, 1.0e6f);
    }
}

// Round 3
// 2451.601 us; speedup vs baseline: 3.7043x; 1.7879x over previous
//
#include <hip/hip_runtime.h>
#include <hip/hip_bf16.h>

#define N_NODES 262144
#define N_EDGES 1048576
#define NC      30
#define ED      13
#define H       256
#define GH      512
#define OUT_C   256
#define NLAYERS 4
#define NGRAPHS 8192

typedef __hip_bfloat16 bf16;
typedef __attribute__((ext_vector_type(8))) short short8;   // 8 bf16 = 4 VGPR
typedef __attribute__((ext_vector_type(4))) float f32x4;

// packed weights: bf16, N-major (Bt[n][k], k contiguous) + fp32 biases
__device__ unsigned short g_W1t[H * H];
__device__ unsigned short g_Wl1t[2][H * H];
__device__ unsigned short g_Wl2t[2][H * H];
__device__ float g_b1[H];
__device__ float g_bl1[GH];
__device__ float g_bl2[OUT_C];
// CSR (device-resident so d_ws only needs hid+hsum = 256 MiB)
__device__ unsigned int g_ssrc[N_EDGES];          // 4 MiB, src ids dst-sorted
__device__ float        g_seat[N_EDGES * ED];     // 52 MiB, eattr dst-sorted
__device__ unsigned int g_rowptr[N_NODES + 1];    // 1 MiB
__device__ unsigned int g_cursor[N_NODES];        // 1 MiB (hist cnt, then cursor)
__device__ unsigned int g_bsum[1024];

__device__ __forceinline__ float hw2f(unsigned short h) {
    return __uint_as_float(((unsigned int)h) << 16);
}
__device__ __forceinline__ float ldf(const void* p, size_t i, bool isbf) {
    return isbf ? hw2f(((const unsigned short*)p)[i]) : ((const float*)p)[i];
}
__device__ __forceinline__ int ldi(const void* p, size_t j, bool is64) {
    return ((const int*)p)[is64 ? 2 * j : j];   // little-endian lo word
}
__device__ __forceinline__ unsigned short bfbits(float f) {
    bf16 b = __float2bfloat16(f);
    return *(unsigned short*)&b;
}
__device__ __forceinline__ float lo16(unsigned int u) { return __uint_as_float(u << 16); }
__device__ __forceinline__ float hi16(unsigned int u) { return __uint_as_float(u & 0xFFFF0000u); }
__device__ __forceinline__ unsigned int pk2(float a, float b) {
    return (unsigned int)bfbits(a) | ((unsigned int)bfbits(b) << 16);
}
// float width sniff: even halfwords. bf16 data -> plausible exponents.
__device__ __forceinline__ bool sniff_bf16(const void* xv) {
    const unsigned short* q = (const unsigned short*)xv;
    int c = 0;
    for (int i = 0; i < 32; ++i) {
        unsigned short h = q[2 * i];
        int e = (h >> 7) & 0xFF;
        c += (h == 0 || (e >= 97 && e <= 141)) ? 1 : 0;
    }
    return c >= 20;
}
// int width sniff: odd 32-bit words all zero <=> int64 (values < 2^31).
__device__ __forceinline__ bool sniff_i64(const void* pv, size_t baseWord) {
    const unsigned int* q = (const unsigned int*)pv;
    int z = 0;
    for (int i = 0; i < 32; ++i) z += (q[baseWord + 2 * i + 1] == 0) ? 1 : 0;
    return z >= 20;
}
// async global->LDS, 16B per lane; dst is wave-uniform base + lane*16
__device__ __forceinline__ void gload_lds16(const void* g, void* l) {
    __builtin_amdgcn_global_load_lds(
        (const __attribute__((address_space(1))) unsigned int*)g,
        (__attribute__((address_space(3))) unsigned int*)l, 16, 0, 0);
}

// ---------------------------------------------------------------- fills
__global__ __launch_bounds__(256) void fill_f4(float4* p, int n4, float val) {
    int i = blockIdx.x * 256 + threadIdx.x;
    int stride = gridDim.x * 256;
    float4 z = make_float4(val, val, val, val);
    for (; i < n4; i += stride) p[i] = z;
}

// ---------------------------------------------------- weight / bias packers
// out[n][k] = in[k0+k][n0+n]  (transpose + bf16-normalize), 256x256 chunk
__global__ __launch_bounds__(256) void pack_wt(const void* __restrict__ in,
        int ldin, int k0, int n0, int which) {
    const bool isbf = sniff_bf16(in);
    unsigned short* outp = which == 0 ? g_W1t
                         : which == 1 ? g_Wl1t[0]
                         : which == 2 ? g_Wl1t[1]
                         : which == 3 ? g_Wl2t[0] : g_Wl2t[1];
    const int n = blockIdx.x, k = threadIdx.x;
    outp[(n << 8) + k] = bfbits(ldf(in, (size_t)(k0 + k) * ldin + n0 + n, isbf));
}
__global__ __launch_bounds__(256) void pack_bias(const void* b1, const void* bl1,
                                                 const void* bl2) {
    const int t = threadIdx.x;
    const bool s1 = sniff_bf16(b1), s2 = sniff_bf16(bl1), s3 = sniff_bf16(bl2);
    g_b1[t]        = ldf(b1,  t,       s1);
    g_bl1[t]       = ldf(bl1, t,       s2);
    g_bl1[t + 256] = ldf(bl1, t + 256, s2);
    g_bl2[t]       = ldf(bl2, t,       s3);
}

// ------------------------------------------------------------- CSR build
// edge_index is launch-invariant across layers: sort edges by dst ONCE.
__global__ __launch_bounds__(256) void csr_zero() {
    g_cursor[blockIdx.x * 256 + threadIdx.x] = 0u;
}
__global__ __launch_bounds__(256) void hist_dst(const void* __restrict__ eidx) {
    const bool is64 = sniff_i64(eidx, 0);
    const int e = blockIdx.x * 256 + threadIdx.x;
    int dst = ldi(eidx, (size_t)N_EDGES + e, is64);
    if ((unsigned)dst >= (unsigned)N_NODES) dst = 0;
    atomicAdd(&g_cursor[dst], 1u);
}
__global__ __launch_bounds__(256) void scan1() {
    __shared__ unsigned int sh[256];
    const int tid = threadIdx.x;
    sh[tid] = g_cursor[blockIdx.x * 256 + tid];
    __syncthreads();
    for (int s = 128; s > 0; s >>= 1) {
        if (tid < s) sh[tid] += sh[tid + s];
        __syncthreads();
    }
    if (tid == 0) g_bsum[blockIdx.x] = sh[0];
}
__global__ __launch_bounds__(256) void scan2() {
    __shared__ unsigned int sh[1024];
    const int tid = threadIdx.x;
    for (int j = tid; j < 1024; j += 256) sh[j] = g_bsum[j];
    __syncthreads();
    if (tid == 0) {
        unsigned int run = 0;
        for (int j = 0; j < 1024; ++j) { unsigned int t = sh[j]; sh[j] = run; run += t; }
    }
    __syncthreads();
    for (int j = tid; j < 1024; j += 256) g_bsum[j] = sh[j];
}
// rowptr = exclusive-scan(cnt); cursor reset to rowptr (cnt lives in g_cursor;
// each thread reads its own slot before any write -> safe in-place).
__global__ __launch_bounds__(256) void scan3() {
    __shared__ unsigned int sh[256];
    const int tid = threadIdx.x;
    const int i = blockIdx.x * 256 + tid;
    const unsigned int v = g_cursor[i];
    sh[tid] = v;
    __syncthreads();
    for (int ofs = 1; ofs < 256; ofs <<= 1) {
        unsigned int t = (tid >= ofs) ? sh[tid - ofs] : 0u;
        __syncthreads();
        sh[tid] += t;
        __syncthreads();
    }
    const unsigned int excl = sh[tid] - v + g_bsum[blockIdx.x];
    g_rowptr[i] = excl;
    g_cursor[i] = excl;
    if (i == N_NODES - 1) g_rowptr[N_NODES] = excl + v;
}
// scatter src-ids and edge_attr rows (fp32-normalized) into dst-sorted order
__global__ __launch_bounds__(256) void scatter_e(
        const void* __restrict__ eidx, const void* __restrict__ eattr) {
    const bool is64 = sniff_i64(eidx, 0);
    const bool isbf = sniff_bf16(eattr);
    const int e = blockIdx.x * 256 + threadIdx.x;
    int src = ldi(eidx, e, is64);
    int dst = ldi(eidx, (size_t)N_EDGES + e, is64);
    if ((unsigned)src >= (unsigned)N_NODES) src = 0;
    if ((unsigned)dst >= (unsigned)N_NODES) dst = 0;
    unsigned int pos = atomicAdd(&g_cursor[dst], 1u);
    if (pos >= (unsigned)N_EDGES) return;   // safety
    g_ssrc[pos] = (unsigned int)src;
#pragma unroll
    for (int k = 0; k < ED; ++k)
        g_seat[(size_t)pos * ED + k] = ldf(eattr, (size_t)e * ED + k, isbf);
}

// ------------------------------------------------- hid = x @ W_nh + b_nh
__global__ __launch_bounds__(256) void node_proj(
        const void* __restrict__ x, const void* __restrict__ W,
        const void* __restrict__ b, bf16* __restrict__ hid) {
    const bool isbf = sniff_bf16(x);
    __shared__ float xs[16 * NC];
    const int m0 = blockIdx.x * 16;
    for (int i = threadIdx.x; i < 16 * NC; i += 256)
        xs[i] = ldf(x, (size_t)m0 * NC + i, isbf);
    __syncthreads();
    const int col = threadIdx.x;
    float w[NC];
#pragma unroll
    for (int k = 0; k < NC; ++k) w[k] = ldf(W, (size_t)k * H + col, isbf);
    const float bias = ldf(b, col, isbf);
#pragma unroll 4
    for (int r = 0; r < 16; ++r) {
        float acc = bias;
#pragma unroll
        for (int k = 0; k < NC; ++k) acc += xs[r * NC + k] * w[k];
        hid[(size_t)(m0 + r) * H + col] = __float2bfloat16(acc);
    }
}

// --------------------------------------------- CSR aggregation (no atomics)
// hsum[n] = hid[n] + sum_{e in in(n)} relu(hid[src(e)] + seat[e]@We + be)
// One wave per node (4 nodes sequential per wave, 16 nodes per block).
// We columns live in REGISTERS (52 VGPR/lane, no LDS, no barriers).
// Lane owns cols {2L, 2L+1, 128+2L, 129+2L}: uint-vectorized hid/hsum access.
// Edge loop is wave-uniform (readfirstlane) -> scalar loads for seat/ssrc.
__global__ __launch_bounds__(256) void gine_agg(
        const void* __restrict__ We, size_t weOff,
        const void* __restrict__ be, size_t beOff,
        const unsigned short* __restrict__ hid,
        unsigned short* __restrict__ hsum) {
    const bool isbf = sniff_bf16(We);
    const int lane = threadIdx.x & 63;
    const int wave = threadIdx.x >> 6;
    const int c0 = 2 * lane;
    float w0[ED], w1[ED], w2[ED], w3[ED];
#pragma unroll
    for (int k = 0; k < ED; ++k) {
        const size_t o = weOff + (size_t)k * H;
        w0[k] = ldf(We, o + c0,       isbf);
        w1[k] = ldf(We, o + c0 + 1,   isbf);
        w2[k] = ldf(We, o + c0 + 128, isbf);
        w3[k] = ldf(We, o + c0 + 129, isbf);
    }
    const float bb0 = ldf(be, beOff + c0,       isbf);
    const float bb1 = ldf(be, beOff + c0 + 1,   isbf);
    const float bb2 = ldf(be, beOff + c0 + 128, isbf);
    const float bb3 = ldf(be, beOff + c0 + 129, isbf);

    const int nbase = blockIdx.x * 16 + wave * 4;
    for (int ni = 0; ni < 4; ++ni) {
        const int node = nbase + ni;
        const unsigned int r0 = __builtin_amdgcn_readfirstlane(g_rowptr[node]);
        const unsigned int r1 = __builtin_amdgcn_readfirstlane(g_rowptr[node + 1]);
        const unsigned short* hn = hid + (size_t)node * H;
        const unsigned int hu0 = *(const unsigned int*)(hn + c0);
        const unsigned int hu1 = *(const unsigned int*)(hn + c0 + 128);
        float a0 = lo16(hu0), a1 = hi16(hu0), a2 = lo16(hu1), a3 = hi16(hu1);
        for (unsigned int e = r0; e < r1; ++e) {
            const unsigned int s = __builtin_amdgcn_readfirstlane(g_ssrc[e]);
            const float* af = g_seat + (size_t)e * ED;
            const unsigned short* hs = hid + (size_t)s * H;
            const unsigned int u0 = *(const unsigned int*)(hs + c0);
            const unsigned int u1 = *(const unsigned int*)(hs + c0 + 128);
            float m0 = bb0, m1 = bb1, m2 = bb2, m3 = bb3;
#pragma unroll
            for (int k = 0; k < ED; ++k) {
                const float a = af[k];
                m0 += a * w0[k]; m1 += a * w1[k];
                m2 += a * w2[k]; m3 += a * w3[k];
            }
            m0 += lo16(u0); m1 += hi16(u0); m2 += lo16(u1); m3 += hi16(u1);
            a0 += fmaxf(m0, 0.f); a1 += fmaxf(m1, 0.f);
            a2 += fmaxf(m2, 0.f); a3 += fmaxf(m3, 0.f);
        }
        unsigned int* ho = (unsigned int*)(hsum + (size_t)node * H);
        ho[lane]      = pk2(a0, a1);
        ho[lane + 64] = pk2(a2, a3);
    }
}

// ------------------------------------------------------------ MFMA GEMM
// C[M,256] = act( widen(A) @ Bt^T + bias )
// Bt: device-global bf16 [256 n][256 k] (k-contiguous), selected by bsel.
// BM=64 BN=256 BK=64; 4 waves; 16x16x32 MFMA; verified C/D layout
// col=lane&15, row=4*(lane>>4)+reg. LDS XOR-swizzle on 16B slots.
// MODE 0: Cb = bf16(act(..)).  MODE 1: fp32 atomicAdd pooled by batch[].
template <int MODE>
__global__ __launch_bounds__(256) void gemm_mfma(
        const unsigned short* __restrict__ A, int bsel,
        unsigned short* __restrict__ Cb, float* __restrict__ Cf,
        const void* __restrict__ batch, size_t batOff, int doRelu, int useBias) {
    __shared__ unsigned short As[64 * 64];    // 8 KB, swizzled
    __shared__ unsigned short Bs[256 * 64];   // 32 KB, n-major [n][k], swizzled
    const int tid  = threadIdx.x;
    const int lane = tid & 63;
    const int wave = tid >> 6;
    const int m0   = blockIdx.x * 64;

    const unsigned short* Bt = bsel == 0 ? g_W1t
                             : bsel == 1 ? g_Wl1t[0]
                             : bsel == 2 ? g_Wl1t[1]
                             : bsel == 3 ? g_Wl2t[0] : g_Wl2t[1];
    const float* bias = bsel == 0 ? g_b1
                      : bsel == 1 ? g_bl1
                      : bsel == 2 ? g_bl1 + 256 : g_bl2;

    const int ar   = tid >> 2;
    const int ac   = (tid & 3) << 4;
    const int awb  = (ar << 7) + (ac << 1);
    const int aswz = (ar & 7) << 4;
    const size_t arow = (size_t)(m0 + ar) * H + ac;
    const int nrow = lane >> 3;
    const int kbu  = ((lane & 7) ^ nrow) << 4;

    f32x4 acc0[8], acc1[8];
    const f32x4 zz = {0.f, 0.f, 0.f, 0.f};
#pragma unroll
    for (int i = 0; i < 8; ++i) { acc0[i] = zz; acc1[i] = zz; }

    const int fr   = lane & 15;
    const int fg   = lane >> 4;
    const int rowb = (wave >> 1) << 5;   // 0 / 32
    const int colb = (wave & 1) << 7;    // 0 / 128

    for (int kt = 0; kt < 4; ++kt) {
#pragma unroll
        for (int j = 0; j < 8; ++j) {
            const int q = (wave << 3) + j;
            gload_lds16((const char*)Bt + (((size_t)(q << 3) + nrow) << 9)
                            + (kt << 7) + kbu,
                        (char*)Bs + (q << 10));
        }
        {
            const size_t aoff = arow + (kt << 6);
            uint4 w0 = *(const uint4*)(A + aoff);
            uint4 w1 = *(const uint4*)(A + aoff + 8);
            *(uint4*)((char*)As + (awb ^ aswz)) = w0;
            *(uint4*)((char*)As + ((awb + 16) ^ aswz)) = w1;
        }
        __syncthreads();   // drains vmcnt (global_load_lds) + lgkmcnt
#pragma unroll
        for (int s = 0; s < 2; ++s) {
            const int kofs = (s << 6) + (fg << 4);
            const int r0 = rowb + fr;
            short8 aF0 = *(const short8*)((const char*)As +
                          ((r0 << 7) + (kofs ^ ((r0 & 7) << 4))));
            short8 aF1 = *(const short8*)((const char*)As +
                          (((r0 + 16) << 7) + (kofs ^ ((r0 & 7) << 4))));
#pragma unroll
            for (int ct = 0; ct < 8; ++ct) {
                const int cc = colb + (ct << 4) + fr;
                short8 bF = *(const short8*)((const char*)Bs +
                             ((cc << 7) + (kofs ^ ((cc & 7) << 4))));
                acc0[ct] = __builtin_amdgcn_mfma_f32_16x16x32_bf16(aF0, bF, acc0[ct], 0, 0, 0);
                acc1[ct] = __builtin_amdgcn_mfma_f32_16x16x32_bf16(aF1, bF, acc1[ct], 0, 0, 0);
            }
        }
        __syncthreads();
    }

    const int crow = m0 + rowb + (fg << 2);
    if (MODE == 0) {
#pragma unroll
        for (int ct = 0; ct < 8; ++ct) {
            const int cc = colb + (ct << 4) + fr;
            const float bc = bias[cc];
#pragma unroll
            for (int r = 0; r < 4; ++r) {
                float v0 = acc0[ct][r] + bc;
                float v1 = acc1[ct][r] + bc;
                if (doRelu) { v0 = fmaxf(v0, 0.f); v1 = fmaxf(v1, 0.f); }
                Cb[(size_t)(crow + r) * H + cc]      = bfbits(v0);
                Cb[(size_t)(crow + 16 + r) * H + cc] = bfbits(v1);
            }
        }
    } else {
        const bool is64 = sniff_i64(batch, N_NODES / 2);
        int ga[5], gb[5];
#pragma unroll
        for (int r = 0; r < 4; ++r) {
            int g0 = ldi(batch, batOff + crow + r, is64);
            int g1 = ldi(batch, batOff + crow + 16 + r, is64);
            ga[r] = ((unsigned)g0 < (unsigned)NGRAPHS) ? g0 : 0;
            gb[r] = ((unsigned)g1 < (unsigned)NGRAPHS) ? g1 : 0;
        }
#pragma unroll
        for (int ct = 0; ct < 8; ++ct) {
            const int cc = colb + (ct << 4) + fr;
            const float bc = useBias ? bias[cc] : 0.f;
            float run0 = 0.f, run1 = 0.f;
#pragma unroll
            for (int r = 0; r < 4; ++r) {
                run0 += acc0[ct][r] + bc;
                if (r == 3 || ga[r + 1] != ga[r]) {
                    atomicAdd(&Cf[(size_t)ga[r] * OUT_C + cc], run0); run0 = 0.f;
                }
                run1 += acc1[ct][r] + bc;
                if (r == 3 || gb[r + 1] != gb[r]) {
                    atomicAdd(&Cf[(size_t)gb[r] * OUT_C + cc], run1); run1 = 0.f;
                }
            }
        }
    }
}

// ---------------------------------------------------------------- launcher
extern "C" void kernel_launch(void* const* d_in, const int* in_sizes, int n_in,
                              void* d_out, int out_size, void* d_ws, size_t ws_size,
                              hipStream_t stream) {
    const void *x = nullptr, *eattr = nullptr, *eidx = nullptr, *batch = nullptr;
    const void *W_nh = nullptr, *W1 = nullptr, *We = nullptr, *be = nullptr;
    const void *Wl1 = nullptr, *Wl2 = nullptr, *bl1 = nullptr;
    const void *z256[3] = {nullptr, nullptr, nullptr};
    int nz = 0;
    for (int i = 0; i < n_in; ++i) {
        switch (in_sizes[i]) {
            case N_NODES * NC:     x     = d_in[i]; break;
            case N_EDGES * ED:     eattr = d_in[i]; break;
            case 2 * N_EDGES:      eidx  = d_in[i]; break;
            case N_NODES:          batch = d_in[i]; break;
            case NC * H:           W_nh  = d_in[i]; break;
            case H * H:            W1    = d_in[i]; break;
            case NLAYERS * ED * H: We    = d_in[i]; break;
            case NLAYERS * H:      be    = d_in[i]; break;
            case H * GH:           if (!Wl1) Wl1 = d_in[i]; else Wl2 = d_in[i]; break;
            case GH:               bl1   = d_in[i]; break;
            case H:                if (nz < 3) z256[nz++] = d_in[i]; break;
            default: break;
        }
    }
    const void* b_nh = z256[0];
    const void* b1   = (nz > 1) ? z256[1] : z256[0];
    const void* bl2  = (nz > 2) ? z256[2] : z256[0];
    float* out = (float*)d_out;   // reference output dtype is FLOAT32

    if (!x || !eattr || !eidx || !batch || !W_nh || !W1 || !We || !be ||
        !Wl1 || !Wl2 || !bl1 || !b_nh) {
        fill_f4<<<1024, 256, 0, stream>>>((float4*)out, NGRAPHS * OUT_C / 4, 2.0e6f);
        return;  // sentinel: size-mapping failed
    }

    const size_t NH = (size_t)N_NODES * H;
    const size_t need = NH * 2 + NH * 2;   // hid + hsum, bf16 = 256 MiB
    if (ws_size < need) {
        fill_f4<<<1024, 256, 0, stream>>>((float4*)out, NGRAPHS * OUT_C / 4, 1.0e6f);
        return;  // sentinel: ws too small
    }
    bf16* hid            = (bf16*)d_ws;
    unsigned short* hsum = (unsigned short*)((char*)d_ws + NH * 2);

    // pack weights (transposed, bf16) + biases (fp32) into device globals
    pack_wt<<<256, 256, 0, stream>>>(W1,  H,     0,   0, 0);
    pack_wt<<<256, 256, 0, stream>>>(Wl1, GH,    0,   0, 1);
    pack_wt<<<256, 256, 0, stream>>>(Wl1, GH,    0, 256, 2);
    pack_wt<<<256, 256, 0, stream>>>(Wl2, OUT_C, 0,   0, 3);
    pack_wt<<<256, 256, 0, stream>>>(Wl2, OUT_C, 256, 0, 4);
    pack_bias<<<1, 256, 0, stream>>>(b1, bl1, bl2);

    // ---- build dst-sorted CSR once per launch (device-global storage)
    csr_zero<<<N_NODES / 256, 256, 0, stream>>>();
    hist_dst<<<N_EDGES / 256, 256, 0, stream>>>(eidx);
    scan1<<<N_NODES / 256, 256, 0, stream>>>();
    scan2<<<1, 256, 0, stream>>>();
    scan3<<<N_NODES / 256, 256, 0, stream>>>();
    scatter_e<<<N_EDGES / 256, 256, 0, stream>>>(eidx, eattr);

    node_proj<<<N_NODES / 16, 256, 0, stream>>>(x, W_nh, b_nh, hid);

    for (int l = 0; l < NLAYERS; ++l) {
        // hsum = hid + agg  (no atomics, no zero-fill, bf16 out)
        gine_agg<<<N_NODES / 16, 256, 0, stream>>>(
            We, (size_t)l * ED * H, be, (size_t)l * H,
            (const unsigned short*)hid, hsum);
        // hid = relu(hsum @ W1 + b1)
        gemm_mfma<0><<<N_NODES / 64, 256, 0, stream>>>(
            hsum, 0, (unsigned short*)hid, nullptr, nullptr, 0, 1, 1);
    }

    // readout; t0 aliases hsum (dead after last layer GEMM consumed it)
    unsigned short* t0 = hsum;
    fill_f4<<<2048, 256, 0, stream>>>((float4*)out, NGRAPHS * OUT_C / 4, 0.f);
    for (int c = 0; c < 2; ++c) {
        gemm_mfma<0><<<N_NODES / 64, 256, 0, stream>>>(
            (const unsigned short*)hid, 1 + c,
            t0, nullptr, nullptr, 0, 1, 1);
        gemm_mfma<1><<<N_NODES / 64, 256, 0, stream>>>(
            t0, 3 + c,
            nullptr, out, batch, 0, 0, c == 0);
    }
}